// Round 7
// baseline (266.910 us; speedup 1.0000x reference)
//
#include <hip/hip_runtime.h>
#include <hip/hip_bf16.h>

typedef float f32x4 __attribute__((ext_vector_type(4)));
typedef short bf16x8 __attribute__((ext_vector_type(8)));

#define MFMA16(a, b, c) __builtin_amdgcn_mfma_f32_16x16x32_bf16(a, b, c, 0, 0, 0)

// Problem constants
constexpr int K1  = 940;   // IN_F
constexpr int LDR = 136;   // LDS row stride (bf16) for A/B/out_s: 272 B -> 4-bank
                           // shift per row -> 2 lanes/bank = conflict-free
constexpr int BCH = 128 * LDR;  // bf16 elements per B chunk (pre-padded global image)

__device__ __forceinline__ float sigf(float x) { return 1.f / (1.f + __expf(-x)); }
__device__ __forceinline__ float tanhfast(float x) { return 2.f / (1.f + __expf(-2.f * x)) - 1.f; }

__device__ __forceinline__ short f2b(float x) {
  __hip_bfloat16 b = __float2bfloat16(x);
  return *reinterpret_cast<short*>(&b);
}

// ---------------------------------------------------------------------------
// Prep: fold swapaxes(-1,-2) into the weights, fp32->bf16, and lay B out
// chunk-major PRE-PADDED: w2cp[c][n][kp], c<8 (K-chunks of 128), n<128
// (rows 100..127 zero), kp<136 (cols 128..135 zero). The fused kernel then
// stages a B chunk as a LINEAR 16-B-per-lane copy into an identical LDS
// image (pad included) -> coalesced global reads AND conflict-free LDS.
// bw2[g][k] = bf16(b_wih[g][k]) zero-padded K 100->128.
// ---------------------------------------------------------------------------
__global__ void prep_kernel(const float* __restrict__ lin_w,
                            const float* __restrict__ b_wih,
                            __hip_bfloat16* __restrict__ w2cp,
                            __hip_bfloat16* __restrict__ bw2) {
  int idx = blockIdx.x * 256 + threadIdx.x;
  if (idx < 8 * BCH) {
    int c = idx / BCH, r = idx - c * BCH;
    int n = r / LDR, kp = r - n * LDR;
    int k = c * 128 + kp;
    float v = 0.f;
    if (n < 100 && kp < 128 && k < K1) {
      int c10 = k / 94, rem = k - c10 * 94;
      int c2 = rem / 47, c47 = rem - c2 * 47;
      int f = c10 * 94 + c47 * 2 + c2;
      v = lin_w[n * K1 + f];
    }
    w2cp[idx] = __float2bfloat16(v);
  } else {
    int i2 = idx - 8 * BCH;
    if (i2 < 64 * 128) {
      int g = i2 >> 7, k = i2 & 127;
      bw2[i2] = __float2bfloat16((k < 100) ? b_wih[g * 100 + k] : 0.f);
    }
  }
}

// ---------------------------------------------------------------------------
// Mega-fused encoder. Block = 512 threads = 8 waves = 64 GEMM rows = 8 seqs.
// Phase A: K-chunked (8 x 128) LDS-double-buffered GEMM. Per chunk, all
// threads stage A (64x128 fp32, 512-B contiguous per 32 lanes, cvt->bf16)
// and B (linear copy of the pre-padded chunk image). issue(c+1) happens
// AFTER the LDS-ready barrier so compute(c) hides its flight; the next
// barrier is the (intended) drain point. Wave w owns M-sub (w>>1)*16 and
// N-half (w&1)*64: acc = 4 f32x4 only -> no spills, no split-K reduction.
// Phase B: xg GEMM from LDS. Phase C: beats LSTM via shfl. Only the 2 MB
// beats tensor touches HBM on the way out.
// ---------------------------------------------------------------------------
__global__ __launch_bounds__(512, 2)
void fused_encoder(const float* __restrict__ ch,
                   const __hip_bfloat16* __restrict__ w2cp,
                   const float* __restrict__ lin_b,
                   const __hip_bfloat16* __restrict__ bw2,
                   const float* __restrict__ bih,
                   const float* __restrict__ bhh,
                   const float* __restrict__ whh,
                   float* __restrict__ beats) {
  __shared__ __align__(16) __hip_bfloat16 As[2][64 * LDR];    // 2 x 17408 B
  __shared__ __align__(16) __hip_bfloat16 Bs[2][128 * LDR];   // 2 x 34816 B
  __shared__ __align__(16) __hip_bfloat16 out_s[64 * LDR];    // 17408 B
  __shared__ float xg_s[64 * 65];                              // 16640 B
  const int tid = threadIdx.x;
  const int w = tid >> 6, lane = tid & 63;
  const int l16 = lane & 15, bq = lane >> 4;
  const int mbase = blockIdx.x * 64;
  const int msub = (w >> 1) * 16;    // this wave's 16-row M-subtile
  const int nb = (w & 1) * 64;       // this wave's N-half (cols nb..nb+63)

  float4 sa[4];   // staged A: idx = p*512+tid -> row=idx>>5, col4=idx&31
  uint4 sb[5];    // staged B: linear 16-B units of the chunk image

  auto issue = [&](int c) {
    const int kb = c * 128;
#pragma unroll
    for (int p = 0; p < 4; ++p) {
      int idx = p * 512 + tid;
      int row = idx >> 5, c4 = idx & 31;
      int col = kb + c4 * 4;
      sa[p] = (col < K1)
                  ? *reinterpret_cast<const float4*>(ch + (long)(mbase + row) * K1 + col)
                  : float4{0.f, 0.f, 0.f, 0.f};
    }
    const __hip_bfloat16* src = w2cp + c * BCH;
#pragma unroll
    for (int p = 0; p < 5; ++p) {
      int idx = p * 512 + tid;
      if (idx < 2176) sb[p] = *reinterpret_cast<const uint4*>(src + idx * 8);
    }
  };

  auto stage = [&](int buf) {
#pragma unroll
    for (int p = 0; p < 4; ++p) {
      int idx = p * 512 + tid;
      int row = idx >> 5, c4 = idx & 31;
      short4 v = {f2b(sa[p].x), f2b(sa[p].y), f2b(sa[p].z), f2b(sa[p].w)};
      *reinterpret_cast<short4*>(&As[buf][row * LDR + c4 * 4]) = v;
    }
#pragma unroll
    for (int p = 0; p < 5; ++p) {
      int idx = p * 512 + tid;
      if (idx < 2176) *reinterpret_cast<uint4*>(&Bs[buf][idx * 8]) = sb[p];
    }
  };

  f32x4 acc[4] = {};
  issue(0);
  for (int c = 0; c < 8; ++c) {
    const int buf = c & 1;
    __syncthreads();  // drains issue(c) (hidden by compute(c-1)); LDS[buf] free
    stage(buf);
    __syncthreads();  // LDS[buf] ready; nothing global in flight here
    if (c < 7) issue(c + 1);  // flies during compute(c)
#pragma unroll
    for (int s = 0; s < 4; ++s) {
      bf16x8 a = *reinterpret_cast<const bf16x8*>(
          &As[buf][(msub + l16) * LDR + s * 32 + bq * 8]);
#pragma unroll
      for (int nt = 0; nt < 4; ++nt) {
        bf16x8 b = *reinterpret_cast<const bf16x8*>(
            &Bs[buf][(nb + nt * 16 + l16) * LDR + s * 32 + bq * 8]);
        acc[nt] = MFMA16(a, b, acc[nt]);
      }
    }
  }

  // Epilogue: bias+relu -> out_s. C-layout col=l16, row=bq*4+r. Cols >=100
  // land as relu(0+0)=0 (B pad rows are zero), giving the K-pad for phase B.
#pragma unroll
  for (int nt = 0; nt < 4; ++nt) {
    const int n = nb + nt * 16 + l16;
    const float bias = (n < 100) ? lin_b[n] : 0.f;
#pragma unroll
    for (int r = 0; r < 4; ++r) {
      float v = fmaxf(acc[nt][r] + bias, 0.f);
      out_s[(msub + bq * 4 + r) * LDR + n] = __float2bfloat16(v);
    }
  }
  __syncthreads();

  // ---- Phase B: xg[64 rows][64 gates] = out_s @ bw2^T + (bih+bhh). ----
  {
    const int rt = w >> 1, gt0 = (w & 1) * 2;
    bf16x8 av[4];
#pragma unroll
    for (int s = 0; s < 4; ++s)
      av[s] = *reinterpret_cast<const bf16x8*>(
          &out_s[(rt * 16 + l16) * LDR + s * 32 + bq * 8]);
    f32x4 xacc[2] = {{0.f, 0.f, 0.f, 0.f}, {0.f, 0.f, 0.f, 0.f}};
#pragma unroll
    for (int g2 = 0; g2 < 2; ++g2) {
      const int gt = gt0 + g2;
#pragma unroll
      for (int s = 0; s < 4; ++s) {
        bf16x8 b = *reinterpret_cast<const bf16x8*>(
            &bw2[(gt * 16 + l16) * 128 + s * 32 + bq * 8]);
        xacc[g2] = MFMA16(av[s], b, xacc[g2]);
      }
    }
#pragma unroll
    for (int g2 = 0; g2 < 2; ++g2) {
      const int gate = (gt0 + g2) * 16 + l16;
      const float bias = bih[gate] + bhh[gate];
#pragma unroll
      for (int r = 0; r < 4; ++r)
        xg_s[(rt * 16 + bq * 4 + r) * 65 + gate] = xacc[g2][r] + bias;
    }
  }
  __syncthreads();

  // ---- Phase C: beats LSTM. Wave w = sequence w (rows w*8..w*8+7). ----
  {
    const int cell = lane & 15;
    float wr[16];
#pragma unroll
    for (int u = 0; u < 16; ++u) wr[u] = whh[lane * 16 + u];
    float xv[8];
#pragma unroll
    for (int t = 0; t < 8; ++t) xv[t] = xg_s[(w * 8 + t) * 65 + lane];
    float h[16];
#pragma unroll
    for (int u = 0; u < 16; ++u) h[u] = 0.f;
    float c = 0.f;
    const int seq = blockIdx.x * 8 + w;
#pragma unroll
    for (int t = 0; t < 8; ++t) {
      float pre = xv[t];
#pragma unroll
      for (int u = 0; u < 16; ++u) pre += wr[u] * h[u];
      float act = (lane >= 32 && lane < 48) ? tanhfast(pre) : sigf(pre);
      float gi = __shfl(act, cell);
      float gf = __shfl(act, cell + 16);
      float gg = __shfl(act, cell + 32);
      float go = __shfl(act, cell + 48);
      c = gf * c + gi * gg;
      float hn = go * tanhfast(c);
#pragma unroll
      for (int u = 0; u < 16; ++u) h[u] = __shfl(hn, u);
      if (lane < 16) beats[seq * 128 + t * 16 + lane] = hn;
    }
  }
}

// ---------------------------------------------------------------------------
// Phase 3: bars biLSTM. 1024 seqs, T=4(beats), H=32. Block = 1 seq,
// 256 threads = 2 dirs x 128 gates. Reads last-frac beats h from d_out (fp32).
// fwd half -> cols 0..31, bwd half -> cols 32..63 (concat order).
// ---------------------------------------------------------------------------
__global__ __launch_bounds__(256)
void bars_bilstm(const float* __restrict__ fwih, const float* __restrict__ fwhh,
                 const float* __restrict__ fbih, const float* __restrict__ fbhh,
                 const float* __restrict__ rwih, const float* __restrict__ rwhh,
                 const float* __restrict__ rbih, const float* __restrict__ rbhh,
                 const float* __restrict__ beats,
                 float* __restrict__ bars) {
  const int tid = threadIdx.x;
  const int dir = tid >> 7, g = tid & 127;
  const int n = blockIdx.x;
  const float* wih = dir ? rwih : fwih;
  const float* whh = dir ? rwhh : fwhh;
  const float bias = dir ? (rbih[g] + rbhh[g]) : (fbih[g] + fbhh[g]);
  float wi[16], wh[32];
#pragma unroll
  for (int u = 0; u < 16; ++u) wi[u] = wih[g * 16 + u];
#pragma unroll
  for (int u = 0; u < 32; ++u) wh[u] = whh[g * 32 + u];
  __shared__ float xbuf[2][16];
  __shared__ float hbuf[2][32];
  __shared__ float gact[2][128];
  float c = 0.f;
  if (g < 32) hbuf[dir][g] = 0.f;
  __syncthreads();
  for (int t = 0; t < 4; ++t) {
    const int tt = dir ? (3 - t) : t;
    if (g < 16) xbuf[dir][g] = beats[((n * 4 + tt) * 8 + 7) * 16 + g];
    __syncthreads();
    float pre = bias;
#pragma unroll
    for (int u = 0; u < 16; ++u) pre += wi[u] * xbuf[dir][u];
#pragma unroll
    for (int u = 0; u < 32; ++u) pre += wh[u] * hbuf[dir][u];
    gact[dir][g] = (g >= 64 && g < 96) ? tanhfast(pre) : sigf(pre);
    __syncthreads();
    if (g < 32) {
      c = gact[dir][32 + g] * c + gact[dir][g] * gact[dir][64 + g];
      float hn = gact[dir][96 + g] * tanhfast(c);
      hbuf[dir][g] = hn;
      bars[(n * 4 + tt) * 64 + dir * 32 + g] = hn;
    }
    __syncthreads();
  }
}

extern "C" void kernel_launch(void* const* d_in, const int* in_sizes, int n_in,
                              void* d_out, int out_size, void* d_ws, size_t ws_size,
                              hipStream_t stream) {
  const float* ch    = (const float*)d_in[0];
  const float* lin_w = (const float*)d_in[1];
  const float* lin_b = (const float*)d_in[2];
  const float* b_wih = (const float*)d_in[3];
  const float* b_whh = (const float*)d_in[4];
  const float* b_bih = (const float*)d_in[5];
  const float* b_bhh = (const float*)d_in[6];
  const float* f_wih = (const float*)d_in[7];
  const float* f_whh = (const float*)d_in[8];
  const float* f_bih = (const float*)d_in[9];
  const float* f_bhh = (const float*)d_in[10];
  const float* r_wih = (const float*)d_in[11];
  const float* r_whh = (const float*)d_in[12];
  const float* r_bih = (const float*)d_in[13];
  const float* r_bhh = (const float*)d_in[14];

  char* ws = (char*)d_ws;
  __hip_bfloat16* w2cp = (__hip_bfloat16*)ws;             // 8*128*136*2 = 278528 B
  __hip_bfloat16* bw2  = (__hip_bfloat16*)(ws + 278528);  // 64*128*2    = 16384 B
  float*          out  = (float*)d_out;

  prep_kernel<<<576, 256, 0, stream>>>(lin_w, b_wih, w2cp, bw2);
  fused_encoder<<<512, 512, 0, stream>>>(ch, w2cp, lin_b, bw2, b_bih, b_bhh,
                                         b_whh, out);
  bars_bilstm<<<1024, 256, 0, stream>>>(f_wih, f_whh, f_bih, f_bhh,
                                        r_wih, r_whh, r_bih, r_bhh,
                                        out, out + 524288);
}